// Round 13
// baseline (453.642 us; speedup 1.0000x reference)
//
#include <hip/hip_runtime.h>

typedef unsigned short u16;
typedef __attribute__((ext_vector_type(8))) short short8;
typedef __attribute__((ext_vector_type(4))) float floatx4;

#define D_MODEL 1024
#define NHEADS 16
#define HD 64
#define BATCH 2
#define SEQ 2048
#define NBLK 512u

static __device__ __forceinline__ u16 f2bf(float f) {
  unsigned int u = __float_as_uint(f);
  u += 0x7fffu + ((u >> 16) & 1u);  // round-to-nearest-even
  return (u16)(u >> 16);
}

static __device__ __forceinline__ void glds16(const u16* g, u16* l) {
  __builtin_amdgcn_global_load_lds(
      (const __attribute__((address_space(1))) void*)g,
      (__attribute__((address_space(3))) void*)l, 16, 0, 0);
}

// device-scope grid barrier: one counter per phase (never reused -> no reset race).
// All blocks guaranteed co-resident: 512 blocks at 2/CU (LDS 51.2<=80KB, VGPR<=256).
static __device__ __forceinline__ void grid_barrier(unsigned* ctr) {
  __syncthreads();
  if (threadIdx.x == 0) {
    __threadfence();  // release prior writes to agent scope (crosses XCD L2s)
    __hip_atomic_fetch_add(ctr, 1u, __ATOMIC_ACQ_REL, __HIP_MEMORY_SCOPE_AGENT);
    while (__hip_atomic_load(ctr, __ATOMIC_ACQUIRE, __HIP_MEMORY_SCOPE_AGENT) < NBLK)
      __builtin_amdgcn_s_sleep(8);
    __threadfence();  // acquire side
  }
  __syncthreads();
}

__global__ void init_ctr(unsigned* ctr) {
  if (threadIdx.x < 4) ctr[threadIdx.x] = 0u;
}

// ---- single persistent kernel: cvt -> QKV+RoPE -> flash v4.2 -> out-proj ----
__global__ __launch_bounds__(256, 2) void fused_mha(
    const float* __restrict__ x, const float* __restrict__ Wq,
    const float* __restrict__ Wk, const float* __restrict__ Wv,
    const float* __restrict__ Wo, float* __restrict__ out,
    u16* __restrict__ xb, u16* __restrict__ wqkv, u16* __restrict__ wo,
    u16* __restrict__ qb, u16* __restrict__ kb, u16* __restrict__ vb,
    u16* __restrict__ ow, unsigned* __restrict__ ctr) {
  __shared__ __align__(16) char smem_raw[51200];
  const int bid = blockIdx.x;  // 0..511
  const int t = threadIdx.x;
  const int lane = t & 63, wv = t >> 6;
  const int lr = lane & 15, qd = lane >> 4;
  const int arow = lane >> 2;
  const int acol = (lane & 3) * 8;

  // ======== phase 0: fp32 -> bf16 convert (16 float4 per thread) ========
  {
#pragma unroll
    for (int s = 0; s < 16; ++s) {
      const int i = bid * 256 + t + s * 131072;
      const int chunk = i >> 18;
      const float* src;
      u16* dst;
      int loc;
      switch (chunk) {
        case 0: case 1: case 2: case 3: src = x;  dst = xb;             loc = i;             break;
        case 4:                         src = Wq; dst = wqkv;           loc = i - (4 << 18); break;
        case 5:                         src = Wk; dst = wqkv + 1048576; loc = i - (5 << 18); break;
        case 6:                         src = Wv; dst = wqkv + 2097152; loc = i - (6 << 18); break;
        default:                        src = Wo; dst = wo;             loc = i - (7 << 18); break;
      }
      const float4 v = ((const float4*)src)[loc];
      ushort4 o;
      o.x = f2bf(v.x); o.y = f2bf(v.y); o.z = f2bf(v.z); o.w = f2bf(v.w);
      ((ushort4*)dst)[loc] = o;
    }
  }
  grid_barrier(&ctr[0]);

  // ======== phase 1: QKV NT-GEMM 64x128 tiles, BK=64, fused RoPE scatter ========
  // 1536 tiles, 3/block: tiles bid, bid+512, bid+1024 -> exactly one Q, K, V tile each.
  {
    u16* As = (u16*)smem_raw;            // [2][64*32]
    u16* Bs = (u16*)(smem_raw + 16384);  // [2][128*32]
    for (int tt = 0; tt < 3; ++tt) {
      const int tile = bid + (tt << 9);
      const int nx = tile >> 6, my = tile & 63;
      const int m0 = my * 64, n0 = nx * 128;

      floatx4 acc[8];
#pragma unroll
      for (int j = 0; j < 8; ++j) acc[j] = (floatx4){0.f, 0.f, 0.f, 0.f};

      for (int kt = 0; kt < 1024; kt += 64) {
        __syncthreads();
#pragma unroll
        for (int kh = 0; kh < 2; ++kh) {
          glds16(&xb[(size_t)(m0 + wv * 16 + arow) * 1024 + kt + kh * 32 + acol],
                 &As[kh * 2048 + wv * 512]);
#pragma unroll
          for (int i2 = 0; i2 < 2; ++i2) {
            const int seg = wv * 2 + i2;
            glds16(&wqkv[(size_t)(n0 + seg * 16 + arow) * 1024 + kt + kh * 32 + acol],
                   &Bs[kh * 4096 + seg * 512]);
          }
        }
        __syncthreads();
#pragma unroll
        for (int kh = 0; kh < 2; ++kh) {
          const short8 af = *(const short8*)&As[kh * 2048 + (wv * 16 + lr) * 32 + qd * 8];
#pragma unroll
          for (int j = 0; j < 8; ++j) {
            const short8 bfr = *(const short8*)&Bs[kh * 4096 + (j * 16 + lr) * 32 + qd * 8];
            acc[j] = __builtin_amdgcn_mfma_f32_16x16x32_bf16(af, bfr, acc[j], 0, 0, 0);
          }
        }
      }

      const int tn = n0 >> 10;  // tile-uniform tensor id
      const int mb = m0 + wv * 16 + qd * 4;
      const int b = mb >> 11;
      if (tn == 2) {            // V: transposed store [B,H,HD,S], 4 consecutive s
        const int s = mb & 2047;
#pragma unroll
        for (int j = 0; j < 8; ++j) {
          const int nn = (n0 + j * 16 + lr) & 1023;
          const int h = nn >> 6, d = nn & 63;
          ushort4 o;
          o.x = f2bf(acc[j][0]); o.y = f2bf(acc[j][1]);
          o.z = f2bf(acc[j][2]); o.w = f2bf(acc[j][3]);
          *(ushort4*)&vb[((size_t)(b * NHEADS + h) * HD + d) * SEQ + s] = o;
        }
      } else {                  // Q or K: fused RoPE (Q pre-scaled by 0.125*log2e)
        u16* dst = (tn == 0) ? qb : kb;
        const float qs = (tn == 0) ? 0.18033688011112042f : 1.0f;
        const int hb = (n0 & 1023) >> 6;
        const float inv0 = __builtin_exp2f(-(float)lr * 0.4152410118609203f);
        const float inv1 = __builtin_exp2f(-(float)(lr + 16) * 0.4152410118609203f);
#pragma unroll
        for (int r = 0; r < 4; ++r) {
          const int sq = (mb + r) & 2047;
          float s0, c0, s1, c1;
          __sincosf((float)sq * inv0, &s0, &c0);
          __sincosf((float)sq * inv1, &s1, &c1);
#pragma unroll
          for (int j = 0; j < 8; ++j) {
            const float v = acc[j][r];
            const float pv = acc[j ^ 2][r];  // rope partner d^32 (same head, j^2)
            const float cc = (j & 1) ? c1 : c0;
            const float ss = (j & 1) ? s1 : s0;
            const float res = (v * cc + ((j & 2) ? pv : -pv) * ss) * qs;
            const int h = hb + (j >> 2);
            dst[((size_t)(b * NHEADS + h) * SEQ + sq) * HD + (j & 3) * 16 + lr] = f2bf(res);
          }
        }
      }
    }
  }
  grid_barrier(&ctr[1]);

  // ======== phase 2: causal flash attention v4.2 (verbatim round-10 dataflow) ========
  {
    u16* KsP = (u16*)smem_raw;             // [2][2][64*32]
    u16* VsP = (u16*)(smem_raw + 16384);   // [2][2][64*32]
    u16* PsP = (u16*)(smem_raw + 32768);   // [4][2][16][72]
    const int bh = bid & 31;
    const int y = bid >> 5;
    const int c = (y < 8) ? (15 - y) : (y - 8);  // CU-balanced pairing
    const int nsteps = 2 * c + 2;
    const int q0w = c * 128 + wv * 32;
    const size_t baseQK = (size_t)bh * SEQ * HD;
    const size_t baseV = (size_t)bh * HD * SEQ;
    const int b = bh >> 4, h = bh & 15;
    const int srow = lane >> 2;
    const int scol = (lane & 3) * 8;

    short8 qf[2][2];
#pragma unroll
    for (int i = 0; i < 2; ++i)
#pragma unroll
      for (int s = 0; s < 2; ++s)
        qf[i][s] = *(const short8*)&qb[baseQK + (size_t)(q0w + i * 16 + lr) * HD + s * 32 + qd * 8];

    float l_i[2] = {0.f, 0.f};
    floatx4 oacc[2][4];
#pragma unroll
    for (int i = 0; i < 2; ++i)
#pragma unroll
      for (int dj = 0; dj < 4; ++dj) oacc[i][dj] = (floatx4){0.f, 0.f, 0.f, 0.f};

    auto stage = [&](int buf, int k0) {
      const int hh = wv & 1;
      if (wv < 2) {
#pragma unroll
        for (int seg = 0; seg < 4; ++seg)
          glds16(&kb[baseQK + (size_t)(k0 + seg * 16 + srow) * HD + hh * 32 + scol],
                 &KsP[(buf * 2 + hh) * 2048 + seg * 512]);
      } else {
#pragma unroll
        for (int seg = 0; seg < 4; ++seg)
          glds16(&vb[baseV + (size_t)(seg * 16 + srow) * SEQ + k0 + hh * 32 + scol],
                 &VsP[(buf * 2 + hh) * 2048 + seg * 512]);
      }
    };

    stage(0, 0);

    for (int kt = 0; kt < nsteps; ++kt) {
      __syncthreads();  // vmcnt drain: buf[kt&1] ready; prev readers done
      if (kt + 1 < nsteps) stage((kt + 1) & 1, (kt + 1) * 64);
      const int k0 = kt * 64;
      if (k0 > q0w + 31) continue;  // wave fully masked (wave-uniform)
      const int buf = kt & 1;

      short8 kf[2][4], vf[2][4];
#pragma unroll
      for (int s = 0; s < 2; ++s)
#pragma unroll
        for (int jj = 0; jj < 4; ++jj)
          kf[s][jj] = *(const short8*)&KsP[(buf * 2 + s) * 2048 + (jj * 16 + lr) * 32 + qd * 8];
#pragma unroll
      for (int s = 0; s < 2; ++s)
#pragma unroll
        for (int dj = 0; dj < 4; ++dj)
          vf[s][dj] = *(const short8*)&VsP[(buf * 2 + s) * 2048 + (dj * 16 + lr) * 32 + qd * 8];

      floatx4 sv[2][4];
#pragma unroll
      for (int i = 0; i < 2; ++i)
#pragma unroll
        for (int jj = 0; jj < 4; ++jj) sv[i][jj] = (floatx4){0.f, 0.f, 0.f, 0.f};
#pragma unroll
      for (int s = 0; s < 2; ++s)
#pragma unroll
        for (int jj = 0; jj < 4; ++jj) {
          sv[1][jj] = __builtin_amdgcn_mfma_f32_16x16x32_bf16(kf[s][jj], qf[1][s], sv[1][jj], 0, 0, 0);
          sv[0][jj] = __builtin_amdgcn_mfma_f32_16x16x32_bf16(kf[s][jj], qf[0][s], sv[0][jj], 0, 0, 0);
        }

#pragma unroll
      for (int i = 0; i < 2; ++i) {
        const int dq = (q0w + i * 16) - k0;  // multiple of 16, >= 0
        if (dq < 63) {                       // diagonal overlap: mask key > q
#pragma unroll
          for (int jj = 0; jj < 4; ++jj)
#pragma unroll
            for (int r = 0; r < 4; ++r)
              if (jj * 16 + qd * 4 + r > dq + lr) sv[i][jj][r] = -1e30f;
        }
        float rs = 0.f;
#pragma unroll
        for (int jj = 0; jj < 4; ++jj) {
          const float p0 = __builtin_exp2f(sv[i][jj][0]);
          const float p1 = __builtin_exp2f(sv[i][jj][1]);
          const float p2 = __builtin_exp2f(sv[i][jj][2]);
          const float p3 = __builtin_exp2f(sv[i][jj][3]);
          rs += (p0 + p1) + (p2 + p3);
          uint2 pk;  // truncating bf16x2 packs, keys ascending
          pk.x = __builtin_amdgcn_perm(__float_as_uint(p1), __float_as_uint(p0), 0x07060302);
          pk.y = __builtin_amdgcn_perm(__float_as_uint(p3), __float_as_uint(p2), 0x07060302);
          *(uint2*)&PsP[((wv * 2 + i) * 16 + lr) * 72 + jj * 16 + qd * 4] = pk;
        }
        l_i[i] += rs;
      }

#pragma unroll
      for (int i = 0; i < 2; ++i) {
        const short8 pf0 = *(const short8*)&PsP[((wv * 2 + i) * 16 + lr) * 72 + qd * 8];
        const short8 pf1 = *(const short8*)&PsP[((wv * 2 + i) * 16 + lr) * 72 + 32 + qd * 8];
#pragma unroll
        for (int dj = 0; dj < 4; ++dj)
          oacc[i][dj] = __builtin_amdgcn_mfma_f32_16x16x32_bf16(pf0, vf[0][dj], oacc[i][dj], 0, 0, 0);
#pragma unroll
        for (int dj = 0; dj < 4; ++dj)
          oacc[i][dj] = __builtin_amdgcn_mfma_f32_16x16x32_bf16(pf1, vf[1][dj], oacc[i][dj], 0, 0, 0);
      }
    }

#pragma unroll
    for (int i = 0; i < 2; ++i) {
      float lf = l_i[i];
      lf += __shfl_xor(lf, 16, 64);
      lf += __shfl_xor(lf, 32, 64);
#pragma unroll
      for (int r = 0; r < 4; ++r) {
        const float linv = 1.f / __shfl(lf, qd * 4 + r, 64);
        const int q = q0w + i * 16 + qd * 4 + r;
#pragma unroll
        for (int dj = 0; dj < 4; ++dj)
          ow[(size_t)(b * SEQ + q) * D_MODEL + h * HD + dj * 16 + lr] = f2bf(oacc[i][dj][r] * linv);
      }
    }
  }
  grid_barrier(&ctr[2]);

  // ======== phase 3: out-proj NT-GEMM 64x128 tiles, BK=64 (1 tile per block) ========
  {
    u16* As = (u16*)smem_raw;            // [2][64*32]
    u16* Bs = (u16*)(smem_raw + 16384);  // [2][128*32]
    const int nx = bid >> 6, my = bid & 63;
    const int m0 = my * 64, n0 = nx * 128;

    floatx4 acc[8];
#pragma unroll
    for (int j = 0; j < 8; ++j) acc[j] = (floatx4){0.f, 0.f, 0.f, 0.f};

    for (int kt = 0; kt < 1024; kt += 64) {
      __syncthreads();
#pragma unroll
      for (int kh = 0; kh < 2; ++kh) {
        glds16(&ow[(size_t)(m0 + wv * 16 + arow) * 1024 + kt + kh * 32 + acol],
               &As[kh * 2048 + wv * 512]);
#pragma unroll
        for (int i2 = 0; i2 < 2; ++i2) {
          const int seg = wv * 2 + i2;
          glds16(&wo[(size_t)(n0 + seg * 16 + arow) * 1024 + kt + kh * 32 + acol],
                 &Bs[kh * 4096 + seg * 512]);
        }
      }
      __syncthreads();
#pragma unroll
      for (int kh = 0; kh < 2; ++kh) {
        const short8 af = *(const short8*)&As[kh * 2048 + (wv * 16 + lr) * 32 + qd * 8];
#pragma unroll
        for (int j = 0; j < 8; ++j) {
          const short8 bfr = *(const short8*)&Bs[kh * 4096 + (j * 16 + lr) * 32 + qd * 8];
          acc[j] = __builtin_amdgcn_mfma_f32_16x16x32_bf16(af, bfr, acc[j], 0, 0, 0);
        }
      }
    }
#pragma unroll
    for (int j = 0; j < 8; ++j)
#pragma unroll
      for (int r = 0; r < 4; ++r)
        out[(size_t)(m0 + wv * 16 + qd * 4 + r) * 1024 + n0 + j * 16 + lr] = acc[j][r];
  }
}

extern "C" void kernel_launch(void* const* d_in, const int* in_sizes, int n_in,
                              void* d_out, int out_size, void* d_ws, size_t ws_size,
                              hipStream_t stream) {
  const float* x  = (const float*)d_in[0];
  const float* Wq = (const float*)d_in[1];
  const float* Wk = (const float*)d_in[2];
  const float* Wv = (const float*)d_in[3];
  const float* Wo = (const float*)d_in[4];
  float* out = (float*)d_out;

  u16* xb = (u16*)d_ws;            // x bf16        [4096,1024]
  u16* wqkv = xb + 4194304;        // Wq|Wk|Wv bf16 [3072,1024]
  u16* wo = wqkv + 3145728;        // Wo bf16       [1024,1024]
  u16* qb = wo + 1048576;          // Q bf16 [B,H,S,HD] (rope'd, *0.125*log2e)
  u16* kb = qb + 4194304;          // K bf16 [B,H,S,HD] (rope'd)
  u16* vb = kb + 4194304;          // V bf16 [B,H,HD,S] (transposed)
  u16* ow = vb + 4194304;          // O bf16 [B,S,D]
  unsigned* ctr = (unsigned*)(ow + 4194304);  // 4 barrier counters

  init_ctr<<<1, 64, 0, stream>>>(ctr);
  void* dummy = nullptr; (void)dummy;
  fused_mha<<<NBLK, 256, 0, stream>>>(x, Wq, Wk, Wv, Wo, out, xb, wqkv, wo,
                                      qb, kb, vb, ow, ctr);
}

// Round 14
// 177.321 us; speedup vs baseline: 2.5583x; 2.5583x over previous
//
#include <hip/hip_runtime.h>

typedef unsigned short u16;
typedef __attribute__((ext_vector_type(8))) short short8;
typedef __attribute__((ext_vector_type(4))) float floatx4;

#define D_MODEL 1024
#define NHEADS 16
#define HD 64
#define BATCH 2
#define SEQ 2048
#define MROWS (BATCH * SEQ)  // 4096

static __device__ __forceinline__ u16 f2bf(float f) {
  unsigned int u = __float_as_uint(f);
  u += 0x7fffu + ((u >> 16) & 1u);  // round-to-nearest-even
  return (u16)(u >> 16);
}

static __device__ __forceinline__ void glds16(const u16* g, u16* l) {
  __builtin_amdgcn_global_load_lds(
      (const __attribute__((address_space(1))) void*)g,
      (__attribute__((address_space(3))) void*)l, 16, 0, 0);
}

// ---------------- fused fp32 -> bf16 convert for all 5 inputs ----------------
__global__ void cvt_all(const float* __restrict__ x, const float* __restrict__ wq,
                        const float* __restrict__ wk, const float* __restrict__ wv,
                        const float* __restrict__ wo, u16* __restrict__ xb,
                        u16* __restrict__ wqkvb, u16* __restrict__ wob) {
  const int i = blockIdx.x * 256 + threadIdx.x;
  const int chunk = i >> 18;
  const float* src;
  u16* dst;
  int loc;
  switch (chunk) {
    case 0: case 1: case 2: case 3: src = x;  dst = xb;              loc = i;              break;
    case 4:                          src = wq; dst = wqkvb;           loc = i - (4 << 18); break;
    case 5:                          src = wk; dst = wqkvb + 1048576; loc = i - (5 << 18); break;
    case 6:                          src = wv; dst = wqkvb + 2097152; loc = i - (6 << 18); break;
    default:                         src = wo; dst = wob;             loc = i - (7 << 18); break;
  }
  const float4 v = ((const float4*)src)[loc];
  ushort4 o;
  o.x = f2bf(v.x); o.y = f2bf(v.y); o.z = f2bf(v.z); o.w = f2bf(v.w);
  ((ushort4*)dst)[loc] = o;
}

// ---------------- bf16 MFMA NT-GEMM 128x128, BK=64, fused RoPE QKV scatter ----------------
__global__ __launch_bounds__(256) void gemm_qkv(
    const u16* __restrict__ A, const u16* __restrict__ B,
    u16* __restrict__ qb, u16* __restrict__ kb, u16* __restrict__ vb, int K) {
  __shared__ u16 As[2][128 * 32];
  __shared__ u16 Bs[2][128 * 32];
  const int t = threadIdx.x;
  const int lane = t & 63;
  const int wv = t >> 6;
  const int wr = wv >> 1, wc = wv & 1;
  const int m0 = blockIdx.y * 128, n0 = blockIdx.x * 128;
  const int qd = lane >> 4, lr = lane & 15;
  const int arow = lane >> 2;
  const int acol = (lane & 3) * 8;

  floatx4 acc[4][4];
#pragma unroll
  for (int i = 0; i < 4; ++i)
#pragma unroll
    for (int j = 0; j < 4; ++j) acc[i][j] = (floatx4){0.f, 0.f, 0.f, 0.f};

  for (int kt = 0; kt < K; kt += 64) {
    __syncthreads();
#pragma unroll
    for (int kh = 0; kh < 2; ++kh) {
#pragma unroll
      for (int i = 0; i < 2; ++i) {
        const int seg = wv * 2 + i;
        glds16(&A[(size_t)(m0 + seg * 16 + arow) * K + kt + kh * 32 + acol], &As[kh][seg * 512]);
        glds16(&B[(size_t)(n0 + seg * 16 + arow) * K + kt + kh * 32 + acol], &Bs[kh][seg * 512]);
      }
    }
    __syncthreads();

#pragma unroll
    for (int kh = 0; kh < 2; ++kh) {
      short8 af[4], bfr[4];
#pragma unroll
      for (int i = 0; i < 4; ++i)
        af[i] = *(const short8*)&As[kh][(wr * 64 + i * 16 + lr) * 32 + qd * 8];
#pragma unroll
      for (int j = 0; j < 4; ++j)
        bfr[j] = *(const short8*)&Bs[kh][(wc * 64 + j * 16 + lr) * 32 + qd * 8];
#pragma unroll
      for (int i = 0; i < 4; ++i)
#pragma unroll
        for (int j = 0; j < 4; ++j)
          acc[i][j] = __builtin_amdgcn_mfma_f32_16x16x32_bf16(af[i], bfr[j], acc[i][j], 0, 0, 0);
    }
  }

  const int tn = n0 >> 10;  // block-uniform tensor id
  if (tn == 2) {            // V: transposed store [B,H,HD,S]
#pragma unroll
    for (int i = 0; i < 4; ++i) {
      const int mb = m0 + wr * 64 + i * 16 + qd * 4;
      const int b = mb >> 11, s = mb & 2047;
#pragma unroll
      for (int j = 0; j < 4; ++j) {
        const int nn = (n0 + wc * 64 + j * 16 + lr) & 1023;
        const int h = nn >> 6, d = nn & 63;
        ushort4 o;
        o.x = f2bf(acc[i][j][0]); o.y = f2bf(acc[i][j][1]);
        o.z = f2bf(acc[i][j][2]); o.w = f2bf(acc[i][j][3]);
        *(ushort4*)&vb[((size_t)(b * NHEADS + h) * HD + d) * SEQ + s] = o;
      }
    }
  } else {                  // Q or K: fused RoPE (Q also scaled by 0.125*log2e)
    u16* dst = (tn == 0) ? qb : kb;
    const float qs = (tn == 0) ? 0.18033688011112042f : 1.0f;
    const int h = ((n0 & 1023) >> 6) + wc;
    const float inv0 = __builtin_exp2f(-(float)lr * 0.4152410118609203f);
    const float inv1 = __builtin_exp2f(-(float)(lr + 16) * 0.4152410118609203f);
#pragma unroll
    for (int i = 0; i < 4; ++i) {
      const int mb = m0 + wr * 64 + i * 16 + qd * 4;
      const int b = mb >> 11;
      const size_t rowbase = (size_t)(b * NHEADS + h) * SEQ;
#pragma unroll
      for (int r = 0; r < 4; ++r) {
        const int sq = (mb + r) & 2047;
        float s0, c0, s1, c1;
        __sincosf((float)sq * inv0, &s0, &c0);
        __sincosf((float)sq * inv1, &s1, &c1);
#pragma unroll
        for (int j = 0; j < 4; ++j) {
          const float v = acc[i][j][r];
          const float pv = acc[i][j ^ 2][r];  // rope partner d^32
          const float cc = (j & 1) ? c1 : c0;
          const float ss = (j & 1) ? s1 : s0;
          const float res = (v * cc + ((j < 2) ? -pv : pv) * ss) * qs;
          dst[(rowbase + sq) * HD + j * 16 + lr] = f2bf(res);
        }
      }
    }
  }
}

// ---------------- bf16 MFMA NT-GEMM 64x64, BK=64 (out-proj): fp32 store ----------------
__global__ __launch_bounds__(256) void gemm_out(
    const u16* __restrict__ A, const u16* __restrict__ B, float* __restrict__ fo,
    int N, int K) {
  __shared__ u16 As[2][64 * 32];
  __shared__ u16 Bs[2][64 * 32];
  const int t = threadIdx.x;
  const int lane = t & 63, wv = t >> 6;
  const int m0 = blockIdx.y * 64, n0 = blockIdx.x * 64;
  const int qd = lane >> 4, lr = lane & 15;
  const int arow = lane >> 2;
  const int acol = (lane & 3) * 8;

  floatx4 acc[4];
#pragma unroll
  for (int j = 0; j < 4; ++j) acc[j] = (floatx4){0.f, 0.f, 0.f, 0.f};

  for (int kt = 0; kt < K; kt += 64) {
    __syncthreads();
#pragma unroll
    for (int kh = 0; kh < 2; ++kh) {
      glds16(&A[(size_t)(m0 + wv * 16 + arow) * K + kt + kh * 32 + acol], &As[kh][wv * 512]);
      glds16(&B[(size_t)(n0 + wv * 16 + arow) * K + kt + kh * 32 + acol], &Bs[kh][wv * 512]);
    }
    __syncthreads();

#pragma unroll
    for (int kh = 0; kh < 2; ++kh) {
      const short8 af = *(const short8*)&As[kh][(wv * 16 + lr) * 32 + qd * 8];
#pragma unroll
      for (int j = 0; j < 4; ++j) {
        const short8 bfr = *(const short8*)&Bs[kh][(j * 16 + lr) * 32 + qd * 8];
        acc[j] = __builtin_amdgcn_mfma_f32_16x16x32_bf16(af, bfr, acc[j], 0, 0, 0);
      }
    }
  }
#pragma unroll
  for (int j = 0; j < 4; ++j)
#pragma unroll
    for (int r = 0; r < 4; ++r)
      fo[(size_t)(m0 + wv * 16 + qd * 4 + r) * N + n0 + j * 16 + lr] = acc[j][r];
}

// ---------------- causal flash attention v6: 128-key staged tiles, 2 sub-steps/barrier ----------------
// v4.2 dataflow preserved; K/V staged as 128-key dbuf tiles (one barrier per 2
// sub-steps -> 17 barrier-steps per CU-pair instead of 34). Ps is ONE per-wave
// region reused sequentially across the two q-subtiles (in-wave LDS program
// order makes write->read->overwrite safe). LDS: K 32K + V 32K + Ps 9.2K = 73K
// -> 2 blocks/CU. nsteps2 = c+1; pair (c,15-c) sums to 17 (CU-balanced).
__global__ __launch_bounds__(256, 2) void flash_mfma(
    const u16* __restrict__ Q, const u16* __restrict__ Kg,
    const u16* __restrict__ Vg, u16* __restrict__ O) {
  __shared__ u16 Ks[2][2][2][64 * 32];  // [buf][key64-sub][d-half][key*32 + d]
  __shared__ u16 Vs[2][2][2][64 * 32];  // [buf][key64-sub][key32-half][d*32 + key]
  __shared__ u16 Ps[4][16][72];         // [wave][q][64 keys + pad], reused per subtile
  const int t = threadIdx.x;
  const int lane = t & 63, wv = t >> 6;
  const int lr = lane & 15, qd = lane >> 4;
  const int bh = blockIdx.x;
  const int y = (int)blockIdx.y;
  const int c = (y < 8) ? (15 - y) : (y - 8);  // CU-balanced pairing
  const int nst2 = c + 1;                      // 128-key steps
  const int q0w = c * 128 + wv * 32;
  const size_t baseQK = (size_t)bh * SEQ * HD;
  const size_t baseV = (size_t)bh * HD * SEQ;
  const int b = bh >> 4, h = bh & 15;
  const int srow = lane >> 2;
  const int scol = (lane & 3) * 8;

  // staging: waves 0/1 -> K subs 0/1; waves 2/3 -> V subs 0/1 (8 glds each)
  auto stage = [&](int buf, int k0) {
    if (wv < 2) {
      const int sub = wv;
#pragma unroll
      for (int hh = 0; hh < 2; ++hh)
#pragma unroll
        for (int seg = 0; seg < 4; ++seg)
          glds16(&Kg[baseQK + (size_t)(k0 + sub * 64 + seg * 16 + srow) * HD + hh * 32 + scol],
                 &Ks[buf][sub][hh][seg * 512]);
    } else {
      const int sub = wv - 2;
#pragma unroll
      for (int hh = 0; hh < 2; ++hh)
#pragma unroll
        for (int seg = 0; seg < 4; ++seg)
          glds16(&Vg[baseV + (size_t)(seg * 16 + srow) * SEQ + k0 + sub * 64 + hh * 32 + scol],
                 &Vs[buf][sub][hh][seg * 512]);
    }
  };

  short8 qf[2][2];
#pragma unroll
  for (int i = 0; i < 2; ++i)
#pragma unroll
    for (int s = 0; s < 2; ++s)
      qf[i][s] = *(const short8*)&Q[baseQK + (size_t)(q0w + i * 16 + lr) * HD + s * 32 + qd * 8];

  float l_i[2] = {0.f, 0.f};
  floatx4 oacc[2][4];
#pragma unroll
  for (int i = 0; i < 2; ++i)
#pragma unroll
    for (int dj = 0; dj < 4; ++dj) oacc[i][dj] = (floatx4){0.f, 0.f, 0.f, 0.f};

  stage(0, 0);

  for (int kt2 = 0; kt2 < nst2; ++kt2) {
    __syncthreads();  // vmcnt drain: buf[kt2&1] ready; prev readers done
    if (kt2 + 1 < nst2) stage((kt2 + 1) & 1, (kt2 + 1) * 128);
    const int buf = kt2 & 1;

#pragma unroll
    for (int sub = 0; sub < 2; ++sub) {
      const int k0 = kt2 * 128 + sub * 64;
      if (k0 > q0w + 31) continue;  // wave fully masked (wave-uniform, no barrier inside)

      short8 kf[2][4], vf[2][4];
#pragma unroll
      for (int s = 0; s < 2; ++s)
#pragma unroll
        for (int jj = 0; jj < 4; ++jj)
          kf[s][jj] = *(const short8*)&Ks[buf][sub][s][(jj * 16 + lr) * 32 + qd * 8];
#pragma unroll
      for (int s = 0; s < 2; ++s)
#pragma unroll
        for (int dj = 0; dj < 4; ++dj)
          vf[s][dj] = *(const short8*)&Vs[buf][sub][s][(dj * 16 + lr) * 32 + qd * 8];

      // S^T MFMAs, both q-subtiles interleaved
      floatx4 sv[2][4];
#pragma unroll
      for (int i = 0; i < 2; ++i)
#pragma unroll
        for (int jj = 0; jj < 4; ++jj) sv[i][jj] = (floatx4){0.f, 0.f, 0.f, 0.f};
#pragma unroll
      for (int s = 0; s < 2; ++s)
#pragma unroll
        for (int jj = 0; jj < 4; ++jj) {
          sv[1][jj] = __builtin_amdgcn_mfma_f32_16x16x32_bf16(kf[s][jj], qf[1][s], sv[1][jj], 0, 0, 0);
          sv[0][jj] = __builtin_amdgcn_mfma_f32_16x16x32_bf16(kf[s][jj], qf[0][s], sv[0][jj], 0, 0, 0);
        }

      // per q-subtile sequentially: mask + exp + pack -> Ps -> PV (Ps reused)
#pragma unroll
      for (int i = 0; i < 2; ++i) {
        const int dq = (q0w + i * 16) - k0;  // multiple of 16, >= 0
        if (dq < 63) {                       // diagonal overlap: mask key > q
#pragma unroll
          for (int jj = 0; jj < 4; ++jj)
#pragma unroll
            for (int r = 0; r < 4; ++r)
              if (jj * 16 + qd * 4 + r > dq + lr) sv[i][jj][r] = -1e30f;
        }
        float rs = 0.f;
#pragma unroll
        for (int jj = 0; jj < 4; ++jj) {
          const float p0 = __builtin_exp2f(sv[i][jj][0]);
          const float p1 = __builtin_exp2f(sv[i][jj][1]);
          const float p2 = __builtin_exp2f(sv[i][jj][2]);
          const float p3 = __builtin_exp2f(sv[i][jj][3]);
          rs += (p0 + p1) + (p2 + p3);
          uint2 pk;  // truncating bf16x2 packs, keys ascending
          pk.x = __builtin_amdgcn_perm(__float_as_uint(p1), __float_as_uint(p0), 0x07060302);
          pk.y = __builtin_amdgcn_perm(__float_as_uint(p3), __float_as_uint(p2), 0x07060302);
          *(uint2*)&Ps[wv][lr][jj * 16 + qd * 4] = pk;
        }
        l_i[i] += rs;

        const short8 pf0 = *(const short8*)&Ps[wv][lr][qd * 8];
        const short8 pf1 = *(const short8*)&Ps[wv][lr][32 + qd * 8];
#pragma unroll
        for (int dj = 0; dj < 4; ++dj)
          oacc[i][dj] = __builtin_amdgcn_mfma_f32_16x16x32_bf16(pf0, vf[0][dj], oacc[i][dj], 0, 0, 0);
#pragma unroll
        for (int dj = 0; dj < 4; ++dj)
          oacc[i][dj] = __builtin_amdgcn_mfma_f32_16x16x32_bf16(pf1, vf[1][dj], oacc[i][dj], 0, 0, 0);
      }
    }
  }

  // epilogue: complete l across quads, redistribute to C/D row layout, store
#pragma unroll
  for (int i = 0; i < 2; ++i) {
    float lf = l_i[i];
    lf += __shfl_xor(lf, 16, 64);
    lf += __shfl_xor(lf, 32, 64);
#pragma unroll
    for (int r = 0; r < 4; ++r) {
      const float linv = 1.f / __shfl(lf, qd * 4 + r, 64);
      const int q = q0w + i * 16 + qd * 4 + r;
#pragma unroll
      for (int dj = 0; dj < 4; ++dj)
        O[(size_t)(b * SEQ + q) * D_MODEL + h * HD + dj * 16 + lr] = f2bf(oacc[i][dj][r] * linv);
    }
  }
}

extern "C" void kernel_launch(void* const* d_in, const int* in_sizes, int n_in,
                              void* d_out, int out_size, void* d_ws, size_t ws_size,
                              hipStream_t stream) {
  const float* x  = (const float*)d_in[0];
  const float* Wq = (const float*)d_in[1];
  const float* Wk = (const float*)d_in[2];
  const float* Wv = (const float*)d_in[3];
  const float* Wo = (const float*)d_in[4];
  float* out = (float*)d_out;

  u16* xb = (u16*)d_ws;            // x bf16        [4096,1024]
  u16* wqkv = xb + 4194304;        // Wq|Wk|Wv bf16 [3072,1024]
  u16* wo = wqkv + 3145728;        // Wo bf16       [1024,1024]
  u16* qb = wo + 1048576;          // Q bf16 [B,H,S,HD] (rope'd, *0.125*log2e)
  u16* kb = qb + 4194304;          // K bf16 [B,H,S,HD] (rope'd)
  u16* vb = kb + 4194304;          // V bf16 [B,H,HD,S] (transposed)
  u16* ow = vb + 4194304;          // O bf16 [B,S,D]

  cvt_all<<<8192, 256, 0, stream>>>(x, Wq, Wk, Wv, Wo, xb, wqkv, wo);
  gemm_qkv<<<dim3(24, 32), 256, 0, stream>>>(xb, wqkv, qb, kb, vb, 1024);
  flash_mfma<<<dim3(32, 16), 256, 0, stream>>>(qb, kb, vb, ow);
  gemm_out<<<dim3(16, 64), 256, 0, stream>>>(ow, wo, out, 1024, 1024);
}